// Round 6
// baseline (593.913 us; speedup 1.0000x reference)
//
#include <hip/hip_runtime.h>
#include <hip/hip_bf16.h>
#include <stdint.h>

#define CSTRIDE 8  // counter padding: 8 ints = 32B (one sector) per counter

__device__ __forceinline__ float rdlane(float v, int l) {
    return __uint_as_float(__builtin_amdgcn_readlane(__float_as_uint(v), l));
}
__device__ __forceinline__ float bf2f(unsigned short u) {
    return __uint_as_float(((unsigned)u) << 16);
}
__device__ __forceinline__ unsigned short f2bf(float f) {
    unsigned u = __float_as_uint(f);
    u += 0x7fffu + ((u >> 16) & 1u);  // RNE
    return (unsigned short)(u >> 16);
}
__device__ __forceinline__ unsigned packbf(float a, float b) {
    return (unsigned)f2bf(a) | ((unsigned)f2bf(b) << 16);
}

// ---------------- zero padded counters + pooled sums ------------------------
__global__ void k_zero(int* __restrict__ cntO, int* __restrict__ cntI,
                       double* __restrict__ sums, int n) {
    int i = blockIdx.x * blockDim.x + threadIdx.x;
    if (i < 128) sums[i] = 0.0;
    if (i < n) { cntO[(size_t)i * CSTRIDE] = 0; cntI[(size_t)i * CSTRIDE] = 0; }
}

// ------- FUSED front: edge MLP (VALU) hides under 2 rank atomics/edge -------
// counters padded to 32B to kill cacheline contention at the coherence point
__global__ __launch_bounds__(256) void k_front(
    const int* __restrict__ ei, const float* __restrict__ ea,
    const float* __restrict__ We1, const float* __restrict__ be1,
    const float* __restrict__ We2, const float* __restrict__ be2,
    unsigned* __restrict__ efp, int* __restrict__ cntO, int* __restrict__ cntI,
    int* __restrict__ rankS, int* __restrict__ rankD, int E) {
    __shared__ float sWe1[128], sbe1[64], sWe2[64 * 6], sbe2[6];
    int t = threadIdx.x;
    if (t < 128) sWe1[t] = We1[t];
    if (t < 64) {
        sbe1[t] = be1[t];
#pragma unroll
        for (int c = 0; c < 6; ++c) sWe2[t * 6 + c] = We2[t * 64 + c];
    }
    if (t < 6) sbe2[t] = be2[t];
    __syncthreads();

    int e = blockIdx.x * blockDim.x + t;
    if (e >= E) return;

    int s = ei[e], d = ei[E + e];
    // issue atomics early; MLP compute below overlaps the RMW round-trip
    int rs = atomicAdd(&cntO[(size_t)s * CSTRIDE], 1);
    int rd = atomicAdd(&cntI[(size_t)d * CSTRIDE], 1);

    float2 aa = ((const float2*)ea)[e];
    float a0 = aa.x, a1 = aa.y;
    float acc[6];
#pragma unroll
    for (int c = 0; c < 6; ++c) acc[c] = sbe2[c];
#pragma unroll
    for (int j = 0; j < 64; ++j) {
        float h = fmaf(a0, sWe1[j], fmaf(a1, sWe1[64 + j], sbe1[j]));
        h = fmaxf(h, 0.f);
#pragma unroll
        for (int c = 0; c < 6; ++c) acc[c] = fmaf(h, sWe2[j * 6 + c], acc[c]);
    }
    unsigned* q = efp + (size_t)e * 3;
    q[0] = packbf(acc[0], acc[1]);
    q[1] = packbf(acc[2], acc[3]);
    q[2] = packbf(acc[4], acc[5]);
    rankS[e] = rs;
    rankD[e] = rd;
}

// ---------------- fused int2 scan pass 1: per-block totals ------------------
__global__ __launch_bounds__(256) void k_scan1(const int* __restrict__ cntO,
                                               const int* __restrict__ cntI,
                                               int2* __restrict__ bsum, int n) {
    __shared__ int2 l[256];
    int i = blockIdx.x * 256 + threadIdx.x;
    l[threadIdx.x] = (i < n) ? make_int2(cntO[(size_t)i * CSTRIDE],
                                         cntI[(size_t)i * CSTRIDE])
                             : make_int2(0, 0);
    __syncthreads();
    for (int s = 128; s > 0; s >>= 1) {
        if (threadIdx.x < s) {
            l[threadIdx.x].x += l[threadIdx.x + s].x;
            l[threadIdx.x].y += l[threadIdx.x + s].y;
        }
        __syncthreads();
    }
    if (threadIdx.x == 0) bsum[blockIdx.x] = l[0];
}

// ------------ fused int2 scan pass 2: exclusive scan of totals --------------
__global__ __launch_bounds__(512) void k_scan2(int2* __restrict__ bsum, int nb,
                                               int* __restrict__ offON,
                                               int* __restrict__ offIN) {
    __shared__ int2 l[512];
    int t = threadIdx.x;
    int2 v = (t < nb) ? bsum[t] : make_int2(0, 0);
    l[t] = v;
    __syncthreads();
    for (int s = 1; s < 512; s <<= 1) {
        int2 tmp = (t >= s) ? l[t - s] : make_int2(0, 0);
        __syncthreads();
        l[t].x += tmp.x; l[t].y += tmp.y;
        __syncthreads();
    }
    if (t < nb) bsum[t] = make_int2(l[t].x - v.x, l[t].y - v.y);  // exclusive
    if (t == 511) { *offON = l[511].x; *offIN = l[511].y; }
}

// ---------------- fused int2 scan pass 3: exact offsets ---------------------
__global__ __launch_bounds__(256) void k_scan3off(const int* __restrict__ cntO,
                                                  const int* __restrict__ cntI,
                                                  const int2* __restrict__ bsum,
                                                  int* __restrict__ offO,
                                                  int* __restrict__ offI, int n) {
    __shared__ int2 l[256];
    int i = blockIdx.x * 256 + threadIdx.x;
    int2 v = (i < n) ? make_int2(cntO[(size_t)i * CSTRIDE],
                                 cntI[(size_t)i * CSTRIDE])
                     : make_int2(0, 0);
    l[threadIdx.x] = v;
    __syncthreads();
    for (int s = 1; s < 256; s <<= 1) {
        int2 tmp = (threadIdx.x >= (unsigned)s) ? l[threadIdx.x - s] : make_int2(0, 0);
        __syncthreads();
        l[threadIdx.x].x += tmp.x; l[threadIdx.x].y += tmp.y;
        __syncthreads();
    }
    if (i < n) {
        int2 bs = bsum[blockIdx.x];
        offO[i] = l[threadIdx.x].x - v.x + bs.x;
        offI[i] = l[threadIdx.x].y - v.y + bs.y;
    }
}

// ------- CSR placement: ZERO atomics, 2 scattered stores/edge ---------------
__global__ __launch_bounds__(256) void k_place(const int* __restrict__ ei,
                                               const int* __restrict__ rankS,
                                               const int* __restrict__ rankD,
                                               const int* __restrict__ offO,
                                               const int* __restrict__ offI,
                                               unsigned* __restrict__ out_eid,
                                               uint2* __restrict__ in_pk, int E) {
    int e = blockIdx.x * blockDim.x + threadIdx.x;
    if (e >= E) return;
    int s = ei[e], d = ei[E + e];
    out_eid[offO[s] + rankS[e]] = (unsigned)e;
    in_pk[offI[d] + rankD[e]] = make_uint2((unsigned)s, (unsigned)e);
}

// ------- per node: nef = sum ef over out+in segments; x'; dinv --------------
__global__ __launch_bounds__(256) void k_nef_x(
    const int* __restrict__ offO, const unsigned* __restrict__ out_eid,
    const int* __restrict__ offI, const uint2* __restrict__ in_pk,
    const unsigned* __restrict__ efp, const float* __restrict__ x,
    float* __restrict__ xp, float* __restrict__ dinv, int n) {
    int i = blockIdx.x * blockDim.x + threadIdx.x;
    if (i >= n) return;
    int bo = offO[i], eo = offO[i + 1];
    int bi = offI[i], eiN = offI[i + 1];
    float a0 = 0.f, a1 = 0.f, a2 = 0.f, a3 = 0.f, a4 = 0.f, a5 = 0.f;
    for (int j = bo; j < eo; ++j) {
        const unsigned* q = efp + (size_t)out_eid[j] * 3;
        unsigned u0 = q[0], u1 = q[1], u2 = q[2];
        a0 += bf2f((unsigned short)u0); a1 += bf2f((unsigned short)(u0 >> 16));
        a2 += bf2f((unsigned short)u1); a3 += bf2f((unsigned short)(u1 >> 16));
        a4 += bf2f((unsigned short)u2); a5 += bf2f((unsigned short)(u2 >> 16));
    }
    for (int j = bi; j < eiN; ++j) {
        const unsigned* q = efp + (size_t)in_pk[j].y * 3;
        unsigned u0 = q[0], u1 = q[1], u2 = q[2];
        a0 += bf2f((unsigned short)u0); a1 += bf2f((unsigned short)(u0 >> 16));
        a2 += bf2f((unsigned short)u1); a3 += bf2f((unsigned short)(u1 >> 16));
        a4 += bf2f((unsigned short)u2); a5 += bf2f((unsigned short)(u2 >> 16));
    }
    int indeg = eiN - bi;
    float degf = (float)((eo - bo) + indeg);
    float inv = 0.5f / fmaxf(degf, 1.f);
    xp[(size_t)i * 6 + 0] = x[(size_t)i * 6 + 0] + a0 * inv;
    xp[(size_t)i * 6 + 1] = x[(size_t)i * 6 + 1] + a1 * inv;
    xp[(size_t)i * 6 + 2] = x[(size_t)i * 6 + 2] + a2 * inv;
    xp[(size_t)i * 6 + 3] = x[(size_t)i * 6 + 3] + a3 * inv;
    xp[(size_t)i * 6 + 4] = x[(size_t)i * 6 + 4] + a4 * inv;
    xp[(size_t)i * 6 + 5] = x[(size_t)i * 6 + 5] + a5 * inv;
    dinv[i] = 1.f / sqrtf(1.f + (float)indeg);
}

// ---------------- layer 1: s1 = bf16(dinv * (x'(N,6) @ W1)) -----------------
__global__ __launch_bounds__(256) void k_mm1(const float* __restrict__ xp,
                                             const float* __restrict__ W1,
                                             const float* __restrict__ dinv,
                                             unsigned short* __restrict__ sOut, int n) {
    int lane = threadIdx.x & 63;
    int wid = (blockIdx.x * blockDim.x + threadIdx.x) >> 6;
    int nw = (gridDim.x * blockDim.x) >> 6;
    float w[6];
#pragma unroll
    for (int c = 0; c < 6; ++c) w[c] = W1[c * 64 + lane];
    for (int i = wid; i < n; i += nw) {
        float xv = (lane < 6) ? xp[(size_t)i * 6 + lane] : 0.f;
        float acc = 0.f;
#pragma unroll
        for (int c = 0; c < 6; ++c) acc = fmaf(rdlane(xv, c), w[c], acc);
        sOut[(size_t)i * 64 + lane] = f2bf(acc * dinv[i]);
    }
}

// ------- FUSED gather+mm, 4-row vectorized: 16 lanes x ushort4 per row ------
__global__ __launch_bounds__(256) void k_gathermm(
    const int* __restrict__ offI, const uint2* __restrict__ in_pk,
    const float* __restrict__ dinv, const unsigned short* __restrict__ sIn,
    const float* __restrict__ bias, const float* __restrict__ W,
    unsigned short* __restrict__ sOut, int n) {
    int lane = threadIdx.x & 63;
    int sub = lane & 15, grp = lane >> 4;
    int wid = (blockIdx.x * blockDim.x + threadIdx.x) >> 6;
    int nw = (gridDim.x * blockDim.x) >> 6;
    float w[64];
#pragma unroll
    for (int c = 0; c < 64; ++c) w[c] = W[c * 64 + lane];
    float4 bb = ((const float4*)bias)[sub];

    for (int i = wid; i < n; i += nw) {
        ushort4 sv = *(const ushort4*)(sIn + (size_t)i * 64 + sub * 4);
        float a0, a1, a2, a3;
        if (grp == 0) { a0 = bf2f(sv.x); a1 = bf2f(sv.y); a2 = bf2f(sv.z); a3 = bf2f(sv.w); }
        else { a0 = a1 = a2 = a3 = 0.f; }
        int b0 = offI[i], e0 = offI[i + 1];
#pragma unroll 4
        for (int j = b0 + grp; j < e0; j += 4) {
            unsigned src = in_pk[j].x;
            ushort4 v = *(const ushort4*)(sIn + (size_t)src * 64 + sub * 4);
            a0 += bf2f(v.x); a1 += bf2f(v.y); a2 += bf2f(v.z); a3 += bf2f(v.w);
        }
        a0 += __shfl_xor(a0, 16); a1 += __shfl_xor(a1, 16);
        a2 += __shfl_xor(a2, 16); a3 += __shfl_xor(a3, 16);
        a0 += __shfl_xor(a0, 32); a1 += __shfl_xor(a1, 32);
        a2 += __shfl_xor(a2, 32); a3 += __shfl_xor(a3, 32);

        float dv = dinv[i];
        float h0 = fmaxf(fmaf(a0, dv, bb.x), 0.f);
        float h1 = fmaxf(fmaf(a1, dv, bb.y), 0.f);
        float h2 = fmaxf(fmaf(a2, dv, bb.z), 0.f);
        float h3 = fmaxf(fmaf(a3, dv, bb.w), 0.f);
        float o = 0.f;
#pragma unroll
        for (int g = 0; g < 16; ++g) {
            o = fmaf(rdlane(h0, g), w[g * 4 + 0], o);
            o = fmaf(rdlane(h1, g), w[g * 4 + 1], o);
            o = fmaf(rdlane(h2, g), w[g * 4 + 2], o);
            o = fmaf(rdlane(h3, g), w[g * 4 + 3], o);
        }
        sOut[(size_t)i * 64 + lane] = f2bf(o * dv);
    }
}

// ------- FUSED final gather + b3 + pooled sum/sumsq, 4-row vectorized -------
__global__ __launch_bounds__(256) void k_gatherreduce(
    const int* __restrict__ offI, const uint2* __restrict__ in_pk,
    const float* __restrict__ dinv, const unsigned short* __restrict__ sIn,
    const float* __restrict__ b3, double* __restrict__ sums, int n) {
    int lane = threadIdx.x & 63;
    int sub = lane & 15, grp = lane >> 4;
    int wv = threadIdx.x >> 6;
    int wid = (blockIdx.x * blockDim.x + threadIdx.x) >> 6;
    int nw = (gridDim.x * blockDim.x) >> 6;
    float4 bb = ((const float4*)b3)[sub];
    double s0 = 0.0, s1 = 0.0, s2_ = 0.0, s3 = 0.0;
    double q0 = 0.0, q1 = 0.0, q2 = 0.0, q3 = 0.0;

    for (int i = wid; i < n; i += nw) {
        ushort4 sv = *(const ushort4*)(sIn + (size_t)i * 64 + sub * 4);
        float a0, a1, a2, a3;
        if (grp == 0) { a0 = bf2f(sv.x); a1 = bf2f(sv.y); a2 = bf2f(sv.z); a3 = bf2f(sv.w); }
        else { a0 = a1 = a2 = a3 = 0.f; }
        int b0 = offI[i], e0 = offI[i + 1];
#pragma unroll 4
        for (int j = b0 + grp; j < e0; j += 4) {
            unsigned src = in_pk[j].x;
            ushort4 v = *(const ushort4*)(sIn + (size_t)src * 64 + sub * 4);
            a0 += bf2f(v.x); a1 += bf2f(v.y); a2 += bf2f(v.z); a3 += bf2f(v.w);
        }
        a0 += __shfl_xor(a0, 16); a1 += __shfl_xor(a1, 16);
        a2 += __shfl_xor(a2, 16); a3 += __shfl_xor(a3, 16);
        a0 += __shfl_xor(a0, 32); a1 += __shfl_xor(a1, 32);
        a2 += __shfl_xor(a2, 32); a3 += __shfl_xor(a3, 32);

        float dv = dinv[i];
        float v0 = fmaf(a0, dv, bb.x);
        float v1 = fmaf(a1, dv, bb.y);
        float v2 = fmaf(a2, dv, bb.z);
        float v3 = fmaf(a3, dv, bb.w);
        s0 += v0; s1 += v1; s2_ += v2; s3 += v3;
        q0 += (double)v0 * v0; q1 += (double)v1 * v1;
        q2 += (double)v2 * v2; q3 += (double)v3 * v3;
    }
    __shared__ double shS[4 * 64], shQ[4 * 64];
    if (grp == 0) {
#pragma unroll
        for (int k = 0; k < 4; ++k) {
            double sk = (k == 0) ? s0 : (k == 1) ? s1 : (k == 2) ? s2_ : s3;
            double qk = (k == 0) ? q0 : (k == 1) ? q1 : (k == 2) ? q2 : q3;
            shS[wv * 64 + sub * 4 + k] = sk;
            shQ[wv * 64 + sub * 4 + k] = qk;
        }
    }
    __syncthreads();
    if (wv == 0) {
        double a = shS[lane] + shS[64 + lane] + shS[128 + lane] + shS[192 + lane];
        double c = shQ[lane] + shQ[64 + lane] + shQ[128 + lane] + shQ[192 + lane];
        unsafeAtomicAdd(&sums[lane], a);
        unsafeAtomicAdd(&sums[64 + lane], c);
    }
}

// ---------------- head MLP + sigmoid (single block) -------------------------
__global__ void k_head(const double* __restrict__ sums,
                       const float* __restrict__ Wp1, const float* __restrict__ bp1,
                       const float* __restrict__ Wp2, const float* __restrict__ bp2,
                       const float* __restrict__ Wp3, const float* __restrict__ bp3,
                       float* __restrict__ out, int n) {
    __shared__ float comb[192], p1[64], p2[32];
    int t = threadIdx.x;
    if (t < 64) {
        double s = sums[t], s2 = sums[64 + t];
        double m = s / n;
        double var = (s2 - s * s / n) / (double)(n - 1);
        float mf = (float)m;
        float sd = (float)sqrt(var > 0.0 ? var : 0.0);
        comb[t] = mf;
        comb[64 + t] = mf;
        comb[128 + t] = sd;
    }
    __syncthreads();
    if (t < 64) {
        float acc = bp1[t];
        for (int k = 0; k < 192; ++k) acc = fmaf(comb[k], Wp1[k * 64 + t], acc);
        p1[t] = fmaxf(acc, 0.f);
    }
    __syncthreads();
    if (t < 32) {
        float acc = bp2[t];
        for (int k = 0; k < 64; ++k) acc = fmaf(p1[k], Wp2[k * 32 + t], acc);
        p2[t] = fmaxf(acc, 0.f);
    }
    __syncthreads();
    if (t == 0) {
        float acc = bp3[0];
        for (int k = 0; k < 32; ++k) acc = fmaf(p2[k], Wp3[k], acc);
        out[0] = 1.f / (1.f + expf(-acc));
    }
}

static inline char* align16(char* p) {
    return (char*)(((uintptr_t)p + 15) & ~(uintptr_t)15);
}

extern "C" void kernel_launch(void* const* d_in, const int* in_sizes, int n_in,
                              void* d_out, int out_size, void* d_ws, size_t ws_size,
                              hipStream_t stream) {
    const float* x   = (const float*)d_in[0];
    const int*   ei  = (const int*)d_in[1];
    const float* ea  = (const float*)d_in[2];
    const float* W1  = (const float*)d_in[3];
    const float* b1  = (const float*)d_in[4];
    const float* W2  = (const float*)d_in[5];
    const float* b2  = (const float*)d_in[6];
    const float* W3  = (const float*)d_in[7];
    const float* b3  = (const float*)d_in[8];
    const float* We1 = (const float*)d_in[9];
    const float* be1 = (const float*)d_in[10];
    const float* We2 = (const float*)d_in[11];
    const float* be2 = (const float*)d_in[12];
    const float* Wp1 = (const float*)d_in[13];
    const float* bp1 = (const float*)d_in[14];
    const float* Wp2 = (const float*)d_in[15];
    const float* bp2 = (const float*)d_in[16];
    const float* Wp3 = (const float*)d_in[17];
    const float* bp3 = (const float*)d_in[18];

    const int N = in_sizes[0] / 6;
    const int E = in_sizes[1] / 2;
    const int nbN = (N + 255) / 256;
    const int nbE = (E + 255) / 256;
    const size_t SB = (size_t)N * 64 * 2;  // one bf16 table = 12.8MB (>= E*4)

    // ---- workspace layout (~76 MB) ----
    char* p = (char*)d_ws;
    double* sums = (double*)p;          p = align16(p + 128 * sizeof(double));
    int* cntO = (int*)p;                p = align16(p + (size_t)N * CSTRIDE * 4);
    int* cntI = (int*)p;                p = align16(p + (size_t)N * CSTRIDE * 4);
    int* offO = (int*)p;                p = align16(p + ((size_t)N + 1) * 4);
    int* offI = (int*)p;                p = align16(p + ((size_t)N + 1) * 4);
    int2* bsum = (int2*)p;              p = align16(p + 512 * 8);
    float* xp = (float*)p;              p = align16(p + (size_t)N * 6 * 4);
    float* dinv = (float*)p;            p = align16(p + (size_t)N * 4);
    uint2* in_pk = (uint2*)p;           p = align16(p + (size_t)E * 8);
    // U1: rankS/rankD die after k_place; reborn as bf16 ping-pong tables
    char* u1 = p;                       p = align16(p + 2 * SB);
    int* rankS = (int*)u1;
    int* rankD = (int*)(u1 + SB);
    unsigned short* sbufA = (unsigned short*)u1;
    unsigned short* sbufB = (unsigned short*)(u1 + SB);
    // U2: efp + out_eid die after k_nef_x
    char* u2 = p;
    unsigned* efp = (unsigned*)u2;
    unsigned* out_eid = (unsigned*)(u2 + (size_t)E * 12);

    const int TB = 256;
    dim3 blk(TB);

    k_zero<<<dim3(nbN), blk, 0, stream>>>(cntO, cntI, sums, N);
    k_front<<<dim3(nbE), blk, 0, stream>>>(ei, ea, We1, be1, We2, be2,
                                           efp, cntO, cntI, rankS, rankD, E);
    k_scan1<<<dim3(nbN), blk, 0, stream>>>(cntO, cntI, bsum, N);
    k_scan2<<<dim3(1), dim3(512), 0, stream>>>(bsum, nbN, offO + N, offI + N);
    k_scan3off<<<dim3(nbN), blk, 0, stream>>>(cntO, cntI, bsum, offO, offI, N);
    k_place<<<dim3(nbE), blk, 0, stream>>>(ei, rankS, rankD, offO, offI, out_eid, in_pk, E);
    k_nef_x<<<dim3(nbN), blk, 0, stream>>>(offO, out_eid, offI, in_pk, efp, x, xp, dinv, N);

    // layer 1 matmul (sbufA aliases rankS — dead after k_place)
    k_mm1<<<dim3(1024), blk, 0, stream>>>(xp, W1, dinv, sbufA, N);
    // layers 2,3 fused gather+mm; final fused gather+reduce
    k_gathermm<<<dim3(2048), blk, 0, stream>>>(offI, in_pk, dinv, sbufA, b1, W2, sbufB, N);
    k_gathermm<<<dim3(2048), blk, 0, stream>>>(offI, in_pk, dinv, sbufB, b2, W3, sbufA, N);
    k_gatherreduce<<<dim3(2048), blk, 0, stream>>>(offI, in_pk, dinv, sbufA, b3, sums, N);
    k_head<<<dim3(1), dim3(64), 0, stream>>>(sums, Wp1, bp1, Wp2, bp2, Wp3, bp3,
                                             (float*)d_out, N);
}

// Round 7
// 543.790 us; speedup vs baseline: 1.0922x; 1.0922x over previous
//
#include <hip/hip_runtime.h>
#include <hip/hip_bf16.h>
#include <stdint.h>

typedef float floatx2 __attribute__((ext_vector_type(2)));

__device__ __forceinline__ float rdlane(float v, int l) {
    return __uint_as_float(__builtin_amdgcn_readlane(__float_as_uint(v), l));
}
__device__ __forceinline__ float bf2f(unsigned short u) {
    return __uint_as_float(((unsigned)u) << 16);
}
__device__ __forceinline__ unsigned short f2bf(float f) {
    unsigned u = __float_as_uint(f);
    u += 0x7fffu + ((u >> 16) & 1u);  // RNE
    return (unsigned short)(u >> 16);
}
__device__ __forceinline__ unsigned packbf(float a, float b) {
    return (unsigned)f2bf(a) | ((unsigned)f2bf(b) << 16);
}
// pack 4 floats -> 4 fp8 e4m3 (HW cvt, RNE)
__device__ __forceinline__ unsigned pk_fp8x4(float a, float b, float c, float d) {
    int u = __builtin_amdgcn_cvt_pk_fp8_f32(a, b, 0, false);
    u = __builtin_amdgcn_cvt_pk_fp8_f32(c, d, u, true);
    return (unsigned)u;
}

// ---------------- zero counters + pooled sums -------------------------------
__global__ void k_zero(int* __restrict__ cntO, int* __restrict__ cntI,
                       double* __restrict__ sums, int n) {
    int i = blockIdx.x * blockDim.x + threadIdx.x;
    if (i < 128) sums[i] = 0.0;
    if (i < n) { cntO[i] = 0; cntI[i] = 0; }
}

// ------- FUSED front: edge MLP (VALU) hides under 2 rank atomics/edge -------
__global__ __launch_bounds__(256) void k_front(
    const int* __restrict__ ei, const float* __restrict__ ea,
    const float* __restrict__ We1, const float* __restrict__ be1,
    const float* __restrict__ We2, const float* __restrict__ be2,
    unsigned* __restrict__ efp, int* __restrict__ cntO, int* __restrict__ cntI,
    int* __restrict__ rankS, int* __restrict__ rankD, int E) {
    __shared__ float sWe1[128], sbe1[64], sWe2[64 * 6], sbe2[6];
    int t = threadIdx.x;
    if (t < 128) sWe1[t] = We1[t];
    if (t < 64) {
        sbe1[t] = be1[t];
#pragma unroll
        for (int c = 0; c < 6; ++c) sWe2[t * 6 + c] = We2[t * 64 + c];
    }
    if (t < 6) sbe2[t] = be2[t];
    __syncthreads();

    int e = blockIdx.x * blockDim.x + t;
    if (e >= E) return;

    int s = ei[e], d = ei[E + e];
    // issue atomics early; MLP compute below overlaps the RMW round-trip
    int rs = atomicAdd(&cntO[s], 1);
    int rd = atomicAdd(&cntI[d], 1);

    float2 aa = ((const float2*)ea)[e];
    float a0 = aa.x, a1 = aa.y;
    float acc[6];
#pragma unroll
    for (int c = 0; c < 6; ++c) acc[c] = sbe2[c];
#pragma unroll
    for (int j = 0; j < 64; ++j) {
        float h = fmaf(a0, sWe1[j], fmaf(a1, sWe1[64 + j], sbe1[j]));
        h = fmaxf(h, 0.f);
#pragma unroll
        for (int c = 0; c < 6; ++c) acc[c] = fmaf(h, sWe2[j * 6 + c], acc[c]);
    }
    unsigned* q = efp + (size_t)e * 3;
    q[0] = packbf(acc[0], acc[1]);
    q[1] = packbf(acc[2], acc[3]);
    q[2] = packbf(acc[4], acc[5]);
    rankS[e] = rs;
    rankD[e] = rd;
}

// ---------------- fused int2 scan pass 1: per-block totals ------------------
__global__ __launch_bounds__(256) void k_scan1(const int* __restrict__ cntO,
                                               const int* __restrict__ cntI,
                                               int2* __restrict__ bsum, int n) {
    __shared__ int2 l[256];
    int i = blockIdx.x * 256 + threadIdx.x;
    l[threadIdx.x] = (i < n) ? make_int2(cntO[i], cntI[i]) : make_int2(0, 0);
    __syncthreads();
    for (int s = 128; s > 0; s >>= 1) {
        if (threadIdx.x < s) {
            l[threadIdx.x].x += l[threadIdx.x + s].x;
            l[threadIdx.x].y += l[threadIdx.x + s].y;
        }
        __syncthreads();
    }
    if (threadIdx.x == 0) bsum[blockIdx.x] = l[0];
}

// ------------ fused int2 scan pass 2: exclusive scan of totals --------------
__global__ __launch_bounds__(512) void k_scan2(int2* __restrict__ bsum, int nb,
                                               int* __restrict__ offON,
                                               int* __restrict__ offIN) {
    __shared__ int2 l[512];
    int t = threadIdx.x;
    int2 v = (t < nb) ? bsum[t] : make_int2(0, 0);
    l[t] = v;
    __syncthreads();
    for (int s = 1; s < 512; s <<= 1) {
        int2 tmp = (t >= s) ? l[t - s] : make_int2(0, 0);
        __syncthreads();
        l[t].x += tmp.x; l[t].y += tmp.y;
        __syncthreads();
    }
    if (t < nb) bsum[t] = make_int2(l[t].x - v.x, l[t].y - v.y);  // exclusive
    if (t == 511) { *offON = l[511].x; *offIN = l[511].y; }
}

// ---------------- fused int2 scan pass 3: exact offsets ---------------------
__global__ __launch_bounds__(256) void k_scan3off(const int* __restrict__ cntO,
                                                  const int* __restrict__ cntI,
                                                  const int2* __restrict__ bsum,
                                                  int* __restrict__ offO,
                                                  int* __restrict__ offI, int n) {
    __shared__ int2 l[256];
    int i = blockIdx.x * 256 + threadIdx.x;
    int2 v = (i < n) ? make_int2(cntO[i], cntI[i]) : make_int2(0, 0);
    l[threadIdx.x] = v;
    __syncthreads();
    for (int s = 1; s < 256; s <<= 1) {
        int2 tmp = (threadIdx.x >= (unsigned)s) ? l[threadIdx.x - s] : make_int2(0, 0);
        __syncthreads();
        l[threadIdx.x].x += tmp.x; l[threadIdx.x].y += tmp.y;
        __syncthreads();
    }
    if (i < n) {
        int2 bs = bsum[blockIdx.x];
        offO[i] = l[threadIdx.x].x - v.x + bs.x;
        offI[i] = l[threadIdx.x].y - v.y + bs.y;
    }
}

// ------- CSR placement with ef embedding: 2 scattered stores/edge -----------
// out_rec[slot] = 12B bf16 ef ; in_rec[slot] = (src, ef01, ef23, ef45) 16B
__global__ __launch_bounds__(256) void k_place(const int* __restrict__ ei,
                                               const int* __restrict__ rankS,
                                               const int* __restrict__ rankD,
                                               const int* __restrict__ offO,
                                               const int* __restrict__ offI,
                                               const unsigned* __restrict__ efp,
                                               unsigned* __restrict__ out_rec,
                                               uint4* __restrict__ in_rec, int E) {
    int e = blockIdx.x * blockDim.x + threadIdx.x;
    if (e >= E) return;
    int s = ei[e], d = ei[E + e];
    const unsigned* q = efp + (size_t)e * 3;
    unsigned u0 = q[0], u1 = q[1], u2 = q[2];
    size_t so = (size_t)(offO[s] + rankS[e]) * 3;
    out_rec[so] = u0; out_rec[so + 1] = u1; out_rec[so + 2] = u2;
    in_rec[offI[d] + rankD[e]] = make_uint4((unsigned)s, u0, u1, u2);
}

// ------- per node: nef streaming sum over out+in records; x'; dinv ----------
__global__ __launch_bounds__(256) void k_nef_x(
    const int* __restrict__ offO, const unsigned* __restrict__ out_rec,
    const int* __restrict__ offI, const uint4* __restrict__ in_rec,
    const float* __restrict__ x,
    float* __restrict__ xp, float* __restrict__ dinv, int n) {
    int i = blockIdx.x * blockDim.x + threadIdx.x;
    if (i >= n) return;
    int bo = offO[i], eo = offO[i + 1];
    int bi = offI[i], eiN = offI[i + 1];
    float a0 = 0.f, a1 = 0.f, a2 = 0.f, a3 = 0.f, a4 = 0.f, a5 = 0.f;
    for (int j = bo; j < eo; ++j) {
        const unsigned* q = out_rec + (size_t)j * 3;
        unsigned u0 = q[0], u1 = q[1], u2 = q[2];
        a0 += bf2f((unsigned short)u0); a1 += bf2f((unsigned short)(u0 >> 16));
        a2 += bf2f((unsigned short)u1); a3 += bf2f((unsigned short)(u1 >> 16));
        a4 += bf2f((unsigned short)u2); a5 += bf2f((unsigned short)(u2 >> 16));
    }
    for (int j = bi; j < eiN; ++j) {
        uint4 r = in_rec[j];
        a0 += bf2f((unsigned short)r.y); a1 += bf2f((unsigned short)(r.y >> 16));
        a2 += bf2f((unsigned short)r.z); a3 += bf2f((unsigned short)(r.z >> 16));
        a4 += bf2f((unsigned short)r.w); a5 += bf2f((unsigned short)(r.w >> 16));
    }
    int indeg = eiN - bi;
    float degf = (float)((eo - bo) + indeg);
    float inv = 0.5f / fmaxf(degf, 1.f);
    xp[(size_t)i * 6 + 0] = x[(size_t)i * 6 + 0] + a0 * inv;
    xp[(size_t)i * 6 + 1] = x[(size_t)i * 6 + 1] + a1 * inv;
    xp[(size_t)i * 6 + 2] = x[(size_t)i * 6 + 2] + a2 * inv;
    xp[(size_t)i * 6 + 3] = x[(size_t)i * 6 + 3] + a3 * inv;
    xp[(size_t)i * 6 + 4] = x[(size_t)i * 6 + 4] + a4 * inv;
    xp[(size_t)i * 6 + 5] = x[(size_t)i * 6 + 5] + a5 * inv;
    dinv[i] = 1.f / sqrtf(1.f + (float)indeg);
}

// ------- layer 1: s1 = fp8(dinv * (x'(N,6) @ W1)), rows = 16 uints ----------
__global__ __launch_bounds__(256) void k_mm1(const float* __restrict__ xp,
                                             const float* __restrict__ W1,
                                             const float* __restrict__ dinv,
                                             unsigned* __restrict__ sOut, int n) {
    int lane = threadIdx.x & 63;
    int sub = lane & 15;
    int wid = (blockIdx.x * blockDim.x + threadIdx.x) >> 6;
    int nw = (gridDim.x * blockDim.x) >> 6;
    float w[6];
#pragma unroll
    for (int c = 0; c < 6; ++c) w[c] = W1[c * 64 + lane];
    for (int i = wid; i < n; i += nw) {
        float xv = (lane < 6) ? xp[(size_t)i * 6 + lane] : 0.f;
        float acc = 0.f;
#pragma unroll
        for (int c = 0; c < 6; ++c) acc = fmaf(rdlane(xv, c), w[c], acc);
        float o = acc * dinv[i];
        float o0 = __shfl(o, sub * 4 + 0);
        float o1 = __shfl(o, sub * 4 + 1);
        float o2 = __shfl(o, sub * 4 + 2);
        float o3 = __shfl(o, sub * 4 + 3);
        if (lane < 16) sOut[(size_t)i * 16 + lane] = pk_fp8x4(o0, o1, o2, o3);
    }
}

// ------- FUSED gather+mm, fp8 rows (64B): 16 lanes x uint per row -----------
__global__ __launch_bounds__(256) void k_gathermm(
    const int* __restrict__ offI, const uint4* __restrict__ in_rec,
    const float* __restrict__ dinv, const unsigned* __restrict__ sIn,
    const float* __restrict__ bias, const float* __restrict__ W,
    unsigned* __restrict__ sOut, int n) {
    int lane = threadIdx.x & 63;
    int sub = lane & 15, grp = lane >> 4;
    int wid = (blockIdx.x * blockDim.x + threadIdx.x) >> 6;
    int nw = (gridDim.x * blockDim.x) >> 6;
    float w[64];
#pragma unroll
    for (int c = 0; c < 64; ++c) w[c] = W[c * 64 + lane];
    float4 bb = ((const float4*)bias)[sub];

    for (int i = wid; i < n; i += nw) {
        unsigned su = sIn[(size_t)i * 16 + sub];
        float a0, a1, a2, a3;
        if (grp == 0) {
            floatx2 lo = __builtin_amdgcn_cvt_pk_f32_fp8(su, false);
            floatx2 hi = __builtin_amdgcn_cvt_pk_f32_fp8(su, true);
            a0 = lo.x; a1 = lo.y; a2 = hi.x; a3 = hi.y;
        } else { a0 = a1 = a2 = a3 = 0.f; }
        int b0 = offI[i], e0 = offI[i + 1];
#pragma unroll 4
        for (int j = b0 + grp; j < e0; j += 4) {
            unsigned src = in_rec[j].x;
            unsigned u = sIn[(size_t)src * 16 + sub];
            floatx2 lo = __builtin_amdgcn_cvt_pk_f32_fp8(u, false);
            floatx2 hi = __builtin_amdgcn_cvt_pk_f32_fp8(u, true);
            a0 += lo.x; a1 += lo.y; a2 += hi.x; a3 += hi.y;
        }
        a0 += __shfl_xor(a0, 16); a1 += __shfl_xor(a1, 16);
        a2 += __shfl_xor(a2, 16); a3 += __shfl_xor(a3, 16);
        a0 += __shfl_xor(a0, 32); a1 += __shfl_xor(a1, 32);
        a2 += __shfl_xor(a2, 32); a3 += __shfl_xor(a3, 32);

        float dv = dinv[i];
        float h0 = fmaxf(fmaf(a0, dv, bb.x), 0.f);
        float h1 = fmaxf(fmaf(a1, dv, bb.y), 0.f);
        float h2 = fmaxf(fmaf(a2, dv, bb.z), 0.f);
        float h3 = fmaxf(fmaf(a3, dv, bb.w), 0.f);
        float o = 0.f;
#pragma unroll
        for (int g = 0; g < 16; ++g) {
            o = fmaf(rdlane(h0, g), w[g * 4 + 0], o);
            o = fmaf(rdlane(h1, g), w[g * 4 + 1], o);
            o = fmaf(rdlane(h2, g), w[g * 4 + 2], o);
            o = fmaf(rdlane(h3, g), w[g * 4 + 3], o);
        }
        o *= dv;
        float o0 = __shfl(o, sub * 4 + 0);
        float o1 = __shfl(o, sub * 4 + 1);
        float o2 = __shfl(o, sub * 4 + 2);
        float o3 = __shfl(o, sub * 4 + 3);
        if (lane < 16) sOut[(size_t)i * 16 + lane] = pk_fp8x4(o0, o1, o2, o3);
    }
}

// ------- FUSED final gather + b3 + pooled sum/sumsq, fp8 rows ---------------
__global__ __launch_bounds__(256) void k_gatherreduce(
    const int* __restrict__ offI, const uint4* __restrict__ in_rec,
    const float* __restrict__ dinv, const unsigned* __restrict__ sIn,
    const float* __restrict__ b3, double* __restrict__ sums, int n) {
    int lane = threadIdx.x & 63;
    int sub = lane & 15, grp = lane >> 4;
    int wv = threadIdx.x >> 6;
    int wid = (blockIdx.x * blockDim.x + threadIdx.x) >> 6;
    int nw = (gridDim.x * blockDim.x) >> 6;
    float4 bb = ((const float4*)b3)[sub];
    double s0 = 0.0, s1 = 0.0, s2_ = 0.0, s3 = 0.0;
    double q0 = 0.0, q1 = 0.0, q2 = 0.0, q3 = 0.0;

    for (int i = wid; i < n; i += nw) {
        unsigned su = sIn[(size_t)i * 16 + sub];
        float a0, a1, a2, a3;
        if (grp == 0) {
            floatx2 lo = __builtin_amdgcn_cvt_pk_f32_fp8(su, false);
            floatx2 hi = __builtin_amdgcn_cvt_pk_f32_fp8(su, true);
            a0 = lo.x; a1 = lo.y; a2 = hi.x; a3 = hi.y;
        } else { a0 = a1 = a2 = a3 = 0.f; }
        int b0 = offI[i], e0 = offI[i + 1];
#pragma unroll 4
        for (int j = b0 + grp; j < e0; j += 4) {
            unsigned src = in_rec[j].x;
            unsigned u = sIn[(size_t)src * 16 + sub];
            floatx2 lo = __builtin_amdgcn_cvt_pk_f32_fp8(u, false);
            floatx2 hi = __builtin_amdgcn_cvt_pk_f32_fp8(u, true);
            a0 += lo.x; a1 += lo.y; a2 += hi.x; a3 += hi.y;
        }
        a0 += __shfl_xor(a0, 16); a1 += __shfl_xor(a1, 16);
        a2 += __shfl_xor(a2, 16); a3 += __shfl_xor(a3, 16);
        a0 += __shfl_xor(a0, 32); a1 += __shfl_xor(a1, 32);
        a2 += __shfl_xor(a2, 32); a3 += __shfl_xor(a3, 32);

        float dv = dinv[i];
        float v0 = fmaf(a0, dv, bb.x);
        float v1 = fmaf(a1, dv, bb.y);
        float v2 = fmaf(a2, dv, bb.z);
        float v3 = fmaf(a3, dv, bb.w);
        s0 += v0; s1 += v1; s2_ += v2; s3 += v3;
        q0 += (double)v0 * v0; q1 += (double)v1 * v1;
        q2 += (double)v2 * v2; q3 += (double)v3 * v3;
    }
    __shared__ double shS[4 * 64], shQ[4 * 64];
    if (grp == 0) {
#pragma unroll
        for (int k = 0; k < 4; ++k) {
            double sk = (k == 0) ? s0 : (k == 1) ? s1 : (k == 2) ? s2_ : s3;
            double qk = (k == 0) ? q0 : (k == 1) ? q1 : (k == 2) ? q2 : q3;
            shS[wv * 64 + sub * 4 + k] = sk;
            shQ[wv * 64 + sub * 4 + k] = qk;
        }
    }
    __syncthreads();
    if (wv == 0) {
        double a = shS[lane] + shS[64 + lane] + shS[128 + lane] + shS[192 + lane];
        double c = shQ[lane] + shQ[64 + lane] + shQ[128 + lane] + shQ[192 + lane];
        unsafeAtomicAdd(&sums[lane], a);
        unsafeAtomicAdd(&sums[64 + lane], c);
    }
}

// ---------------- head MLP + sigmoid (single block) -------------------------
__global__ void k_head(const double* __restrict__ sums,
                       const float* __restrict__ Wp1, const float* __restrict__ bp1,
                       const float* __restrict__ Wp2, const float* __restrict__ bp2,
                       const float* __restrict__ Wp3, const float* __restrict__ bp3,
                       float* __restrict__ out, int n) {
    __shared__ float comb[192], p1[64], p2[32];
    int t = threadIdx.x;
    if (t < 64) {
        double s = sums[t], s2 = sums[64 + t];
        double m = s / n;
        double var = (s2 - s * s / n) / (double)(n - 1);
        float mf = (float)m;
        float sd = (float)sqrt(var > 0.0 ? var : 0.0);
        comb[t] = mf;
        comb[64 + t] = mf;
        comb[128 + t] = sd;
    }
    __syncthreads();
    if (t < 64) {
        float acc = bp1[t];
        for (int k = 0; k < 192; ++k) acc = fmaf(comb[k], Wp1[k * 64 + t], acc);
        p1[t] = fmaxf(acc, 0.f);
    }
    __syncthreads();
    if (t < 32) {
        float acc = bp2[t];
        for (int k = 0; k < 64; ++k) acc = fmaf(p1[k], Wp2[k * 32 + t], acc);
        p2[t] = fmaxf(acc, 0.f);
    }
    __syncthreads();
    if (t == 0) {
        float acc = bp3[0];
        for (int k = 0; k < 32; ++k) acc = fmaf(p2[k], Wp3[k], acc);
        out[0] = 1.f / (1.f + expf(-acc));
    }
}

static inline char* align16(char* p) {
    return (char*)(((uintptr_t)p + 15) & ~(uintptr_t)15);
}

extern "C" void kernel_launch(void* const* d_in, const int* in_sizes, int n_in,
                              void* d_out, int out_size, void* d_ws, size_t ws_size,
                              hipStream_t stream) {
    const float* x   = (const float*)d_in[0];
    const int*   ei  = (const int*)d_in[1];
    const float* ea  = (const float*)d_in[2];
    const float* W1  = (const float*)d_in[3];
    const float* b1  = (const float*)d_in[4];
    const float* W2  = (const float*)d_in[5];
    const float* b2  = (const float*)d_in[6];
    const float* W3  = (const float*)d_in[7];
    const float* b3  = (const float*)d_in[8];
    const float* We1 = (const float*)d_in[9];
    const float* be1 = (const float*)d_in[10];
    const float* We2 = (const float*)d_in[11];
    const float* be2 = (const float*)d_in[12];
    const float* Wp1 = (const float*)d_in[13];
    const float* bp1 = (const float*)d_in[14];
    const float* Wp2 = (const float*)d_in[15];
    const float* bp2 = (const float*)d_in[16];
    const float* Wp3 = (const float*)d_in[17];
    const float* bp3 = (const float*)d_in[18];

    const int N = in_sizes[0] / 6;
    const int E = in_sizes[1] / 2;
    const int nbN = (N + 255) / 256;
    const int nbE = (E + 255) / 256;
    const size_t SB = (size_t)N * 64;  // one fp8 table = 6.4MB (== E*4)

    // ---- workspace layout (~81 MB) ----
    char* p = (char*)d_ws;
    double* sums = (double*)p;          p = align16(p + 128 * sizeof(double));
    int* cntO = (int*)p;                p = align16(p + (size_t)N * 4);
    int* cntI = (int*)p;                p = align16(p + (size_t)N * 4);
    int* offO = (int*)p;                p = align16(p + ((size_t)N + 1) * 4);
    int* offI = (int*)p;                p = align16(p + ((size_t)N + 1) * 4);
    int2* bsum = (int2*)p;              p = align16(p + 512 * 8);
    float* xp = (float*)p;              p = align16(p + (size_t)N * 6 * 4);
    float* dinv = (float*)p;            p = align16(p + (size_t)N * 4);
    uint4* in_rec = (uint4*)p;          p = align16(p + (size_t)E * 16);
    // U1: rankS/rankD (E*4 each) die after k_place; reborn as fp8 ping-pong
    char* u1 = p;                       p = align16(p + 2 * ((SB + 15) & ~(size_t)15));
    int* rankS = (int*)u1;
    int* rankD = (int*)(u1 + ((SB + 15) & ~(size_t)15));
    unsigned* sbufA = (unsigned*)rankS;
    unsigned* sbufB = (unsigned*)rankD;
    // U2: efp (E*12) + out_rec (E*12) die after k_nef_x
    char* u2 = p;
    unsigned* efp = (unsigned*)u2;
    unsigned* out_rec = (unsigned*)(u2 + (size_t)E * 12);

    const int TB = 256;
    dim3 blk(TB);

    k_zero<<<dim3(nbN), blk, 0, stream>>>(cntO, cntI, sums, N);
    k_front<<<dim3(nbE), blk, 0, stream>>>(ei, ea, We1, be1, We2, be2,
                                           efp, cntO, cntI, rankS, rankD, E);
    k_scan1<<<dim3(nbN), blk, 0, stream>>>(cntO, cntI, bsum, N);
    k_scan2<<<dim3(1), dim3(512), 0, stream>>>(bsum, nbN, offO + N, offI + N);
    k_scan3off<<<dim3(nbN), blk, 0, stream>>>(cntO, cntI, bsum, offO, offI, N);
    k_place<<<dim3(nbE), blk, 0, stream>>>(ei, rankS, rankD, offO, offI, efp,
                                           out_rec, in_rec, E);
    k_nef_x<<<dim3(nbN), blk, 0, stream>>>(offO, out_rec, offI, in_rec, x, xp, dinv, N);

    // layer 1 matmul (sbufA aliases rankS — dead after k_place)
    k_mm1<<<dim3(1024), blk, 0, stream>>>(xp, W1, dinv, sbufA, N);
    // layers 2,3 fused gather+mm; final fused gather+reduce
    k_gathermm<<<dim3(2048), blk, 0, stream>>>(offI, in_rec, dinv, sbufA, b1, W2, sbufB, N);
    k_gathermm<<<dim3(2048), blk, 0, stream>>>(offI, in_rec, dinv, sbufB, b2, W3, sbufA, N);
    k_gatherreduce<<<dim3(2048), blk, 0, stream>>>(offI, in_rec, dinv, sbufA, b3, sums, N);
    k_head<<<dim3(1), dim3(64), 0, stream>>>(sums, Wp1, bp1, Wp2, bp2, Wp3, bp3,
                                             (float*)d_out, N);
}